// Round 7
// baseline (430.474 us; speedup 1.0000x reference)
//
#include <hip/hip_runtime.h>
#include <math.h>

#define SS 2048
#define QP 72   // bf16 pitch sQ (48 rows/head)
#define KP 72   // bf16 pitch sK (80 rows/head)
#define VP 72   // bf16 pitch sVt (64 d-rows/head)
#define SP 84   // f32 pitch sS (48 rows/head, 80 cols)
#define PP 72   // bf16 pitch sP (32 rows/head, 64 cols)

typedef __attribute__((ext_vector_type(8))) short s8v;
typedef __attribute__((ext_vector_type(4))) float f4v;

__device__ __forceinline__ unsigned short f2b(float x) {
    union { float f; unsigned u; } v; v.f = x;
    unsigned r = v.u + 0x7FFFu + ((v.u >> 16) & 1u);
    return (unsigned short)(r >> 16);
}

__device__ __forceinline__ unsigned long long pack4(float4 v) {
    return (unsigned long long)f2b(v.x) | ((unsigned long long)f2b(v.y) << 16)
         | ((unsigned long long)f2b(v.z) << 32) | ((unsigned long long)f2b(v.w) << 48);
}

__global__ __launch_bounds__(512, 2)
void mta_v7(const float* __restrict__ Q, const float* __restrict__ K,
            const float* __restrict__ V, const float* __restrict__ CW,
            const float* __restrict__ CB, const float* __restrict__ MIX,
            const float* __restrict__ GAM, const float* __restrict__ BET,
            float* __restrict__ OUT)
{
    __shared__ __align__(16) unsigned short sQ[96 * QP];       // 13824 B
    __shared__ __align__(16) unsigned short sK[2][160 * KP];   // 2 x 23040 B
    __shared__ __align__(16) unsigned short sVt[2][128 * VP];  // 2 x 18432 B
    __shared__ __align__(16) float sS[96 * SP];                // 32256 B (reused as sO, pitch 68)
    __shared__ __align__(16) unsigned short sP[64 * PP];       // 9216 B
    __shared__ float sResc[2][32];
    __shared__ float sL[2][32];
    // total ~138.8 KB -> hardware-guaranteed 1 block/CU

    const int tid = threadIdx.x;
    const int g = blockIdx.x & 7;
    const int u = blockIdx.x >> 3;   // 0..31

    const int wv = tid >> 6, lane = tid & 63;
    const int lrow = lane & 15;            // MFMA A/B row, C col
    const int lk8 = (lane >> 4) << 3;      // MFMA k-offset
    const int crow4 = (lane >> 4) << 2;    // MFMA C row base

    // conv/softmax mapping: 2 heads x 32 rows x 8 key-octs
    const int ch = tid >> 8;
    const int cq = (tid >> 3) & 31;
    const int ck = tid & 7;

    // PV wave role: (i = source head, j = dest head, kh = key half)
    const int i_pv = wv >> 2, j_pv = (wv >> 1) & 1, kh = wv & 1;

    // conv weights + bias + mix coefficient in registers (ti-invariant)
    float w[66];
#pragma unroll
    for (int z = 0; z < 66; ++z) w[z] = CW[(2 * g + ch) * 66 + z];
    const float bias = CB[2 * g + ch];
    const float mixc = MIX[g * 4 + i_pv * 2 + j_pv];

    const float4* Q4 = (const float4*)Q;
    const float4* K4 = (const float4*)K;
    const float4* V4 = (const float4*)V;

    for (int ti = 0; ti < 2; ++ti) {
        const int tile = ti ? u : (63 - u);   // per-block iteration total constant (33)
        const int q0 = tile << 5;
        __syncthreads(); // P0: prev-ti epilogue/PV fully done before restaging

        // ---- stage extended Q tile (rows q0-2 .. q0+45), bf16 ----
        for (int idx = tid; idx < 1536; idx += 512) {
            int h = idx / 768, rem = idx - h * 768;
            int e = rem >> 4, d4 = rem & 15;
            int r = q0 - 2 + e;
            float4 val = make_float4(0.f, 0.f, 0.f, 0.f);
            if (r >= 0 && r < SS) val = Q4[((2 * g + h) * SS + r) * 16 + d4];
            *(unsigned long long*)&sQ[(h * 48 + e) * QP + (d4 << 2)] = pack4(val);
        }
        // ---- direct-stage K/V buffer 0 (k0 = 0) ----
        for (int idx = tid; idx < 2560; idx += 512) {
            int h = idx / 1280, rem = idx - h * 1280;
            int e = rem >> 4, d4 = rem & 15;
            int c = -5 + e;
            float4 val = make_float4(0.f, 0.f, 0.f, 0.f);
            if (e < 74 && c >= 0 && c < SS) val = K4[((2 * g + h) * SS + c) * 16 + d4];
            *(unsigned long long*)&sK[0][(h * 80 + e) * KP + (d4 << 2)] = pack4(val);
        }
        for (int idx = tid; idx < 2048; idx += 512) {
            int h = idx >> 10, d4 = (idx >> 6) & 15, kk = idx & 63;
            float4 val = V4[((2 * g + h) * SS + kk) * 16 + d4];
            int d = d4 << 2;
            sVt[0][(h * 64 + d + 0) * VP + kk] = f2b(val.x);
            sVt[0][(h * 64 + d + 1) * VP + kk] = f2b(val.y);
            sVt[0][(h * 64 + d + 2) * VP + kk] = f2b(val.z);
            sVt[0][(h * 64 + d + 3) * VP + kk] = f2b(val.w);
        }

        f4v acc[2][4];
#pragma unroll
        for (int mt = 0; mt < 2; ++mt)
#pragma unroll
            for (int nt = 0; nt < 4; ++nt) acc[mt][nt] = f4v{0.f, 0.f, 0.f, 0.f};
        float m_run = -INFINITY, l_run = 0.f;
        int cur = 0;

        __syncthreads(); // P1: buffer 0 + Q staged

        const int iters = (tile >> 1) + 1;   // 64 keys per iteration
        for (int it = 0; it < iters; ++it) {
            const int k0 = it << 6;
            const bool pf = (it + 1) < iters;
            const int k0n = (it + 1) << 6;

            // ---- (A) issue prefetch loads for iter it+1 into registers ----
            float4 kreg[5], vreg[4];
#pragma unroll
            for (int n = 0; n < 5; ++n) {
                int idx = tid + (n << 9);
                int h = idx / 1280, rem = idx - h * 1280;
                int e = rem >> 4, d4 = rem & 15;
                int c = k0n - 5 + e;
                kreg[n] = make_float4(0.f, 0.f, 0.f, 0.f);
                if (pf && e < 74 && c >= 0 && c < SS)
                    kreg[n] = K4[((2 * g + h) * SS + c) * 16 + d4];
            }
#pragma unroll
            for (int n = 0; n < 4; ++n) {
                int idx = tid + (n << 9);
                int h = idx >> 10, d4 = (idx >> 6) & 15, kk = idx & 63;
                vreg[n] = make_float4(0.f, 0.f, 0.f, 0.f);
                if (pf)
                    vreg[n] = V4[((2 * g + h) * SS + k0n + kk) * 16 + d4];
            }

            // ---- (B) scores: 2 heads x 3 m-tiles x 5 n-tiles, K=64 ----
            for (int job = wv; job < 30; job += 8) {
                int h = job / 15, r15 = job - h * 15;
                int mt = r15 / 5, nt = r15 - mt * 5;
                const unsigned short* ap = &sQ[(h * 48 + mt * 16 + lrow) * QP + lk8];
                const unsigned short* bp = &sK[cur][(h * 80 + nt * 16 + lrow) * KP + lk8];
                f4v c = f4v{0.f, 0.f, 0.f, 0.f};
                c = __builtin_amdgcn_mfma_f32_16x16x32_bf16(*(const s8v*)ap,
                                                            *(const s8v*)bp, c, 0, 0, 0);
                c = __builtin_amdgcn_mfma_f32_16x16x32_bf16(*(const s8v*)(ap + 32),
                                                            *(const s8v*)(bp + 32), c, 0, 0, 0);
                int col = nt * 16 + lrow;
                int cab = k0 - 5 + col;
                int rbase = mt * 16 + crow4;
#pragma unroll
                for (int r = 0; r < 4; ++r)
                    sS[(h * 48 + rbase + r) * SP + col] = (cab <= q0 - 2 + rbase + r) ? c[r] * 0.125f : 0.f;
            }
            __syncthreads(); // X: sS ready; prev PV done with sP/sResc

            // ---- (C) conv (8 keys/thread, reg weights) + re-mask + online softmax ----
            {
                const int c0 = ck << 3;
                float a8[8];
#pragma unroll
                for (int kk = 0; kk < 8; ++kk) a8[kk] = bias;
#pragma unroll
                for (int i = 0; i < 6; ++i) {
                    const float* base = &sS[(ch * 48 + cq + i) * SP + c0];
                    float4 x0 = *(const float4*)&base[0];
                    float4 x1 = *(const float4*)&base[4];
                    float4 x2 = *(const float4*)&base[8];
                    float4 x3 = *(const float4*)&base[12];
                    float4 x4 = *(const float4*)&base[16];
                    float s[20] = {x0.x, x0.y, x0.z, x0.w, x1.x, x1.y, x1.z, x1.w,
                                   x2.x, x2.y, x2.z, x2.w, x3.x, x3.y, x3.z, x3.w,
                                   x4.x, x4.y, x4.z, x4.w};
#pragma unroll
                    for (int kk = 0; kk < 8; ++kk)
#pragma unroll
                        for (int jj = 0; jj < 11; ++jj)
                            a8[kk] = fmaf(w[i * 11 + jj], s[kk + jj], a8[kk]);
                }
                const int r_abs = q0 + cq;
                float tmax = -INFINITY;
#pragma unroll
                for (int kk = 0; kk < 8; ++kk) {
                    int cab = k0 + c0 + kk;
                    if (cab > r_abs) a8[kk] = -1e9f;
                    tmax = fmaxf(tmax, a8[kk]);
                }
                tmax = fmaxf(tmax, __shfl_xor(tmax, 1));
                tmax = fmaxf(tmax, __shfl_xor(tmax, 2));
                tmax = fmaxf(tmax, __shfl_xor(tmax, 4));
                float mnew = fmaxf(m_run, tmax);
                float resc = __expf(m_run - mnew); // first iter: exp(-inf)=0
                float p[8];
                float psum = 0.f;
#pragma unroll
                for (int kk = 0; kk < 8; ++kk) {
                    p[kk] = __expf(a8[kk] - mnew);
                    psum += p[kk];
                }
                psum += __shfl_xor(psum, 1);
                psum += __shfl_xor(psum, 2);
                psum += __shfl_xor(psum, 4);
                l_run = l_run * resc + psum;
                m_run = mnew;
                if (ck == 0) sResc[ch][cq] = resc;
                s8v pv;
#pragma unroll
                for (int kk = 0; kk < 8; ++kk) pv[kk] = (short)f2b(p[kk]);
                *(s8v*)&sP[(ch * 32 + cq) * PP + c0] = pv;
            }

            // ---- (D) write prefetched K/V into the other buffer ----
            if (pf) {
                const int nxt = cur ^ 1;
#pragma unroll
                for (int n = 0; n < 5; ++n) {
                    int idx = tid + (n << 9);
                    int h = idx / 1280, rem = idx - h * 1280;
                    int e = rem >> 4, d4 = rem & 15;
                    *(unsigned long long*)&sK[nxt][(h * 80 + e) * KP + (d4 << 2)] = pack4(kreg[n]);
                }
#pragma unroll
                for (int n = 0; n < 4; ++n) {
                    int idx = tid + (n << 9);
                    int h = idx >> 10, d4 = (idx >> 6) & 15, kk = idx & 63;
                    int d = d4 << 2;
                    sVt[nxt][(h * 64 + d + 0) * VP + kk] = f2b(vreg[n].x);
                    sVt[nxt][(h * 64 + d + 1) * VP + kk] = f2b(vreg[n].y);
                    sVt[nxt][(h * 64 + d + 2) * VP + kk] = f2b(vreg[n].z);
                    sVt[nxt][(h * 64 + d + 3) * VP + kk] = f2b(vreg[n].w);
                }
            }
            __syncthreads(); // Y: sP/sResc ready; next-buffer staged

            // ---- (E) PV: wave (i,j,kh): acc += P_i[kh half] @ V_j ----
            {
#pragma unroll
                for (int mt = 0; mt < 2; ++mt)
#pragma unroll
                    for (int r = 0; r < 4; ++r) {
                        float f = sResc[i_pv][mt * 16 + crow4 + r];
#pragma unroll
                        for (int nt = 0; nt < 4; ++nt) acc[mt][nt][r] *= f;
                    }
#pragma unroll
                for (int mt = 0; mt < 2; ++mt) {
                    s8v a = *(const s8v*)&sP[(i_pv * 32 + mt * 16 + lrow) * PP + (kh << 5) + lk8];
#pragma unroll
                    for (int nt = 0; nt < 4; ++nt) {
                        s8v b = *(const s8v*)&sVt[cur][(j_pv * 64 + nt * 16 + lrow) * VP + (kh << 5) + lk8];
                        acc[mt][nt] = __builtin_amdgcn_mfma_f32_16x16x32_bf16(a, b, acc[mt][nt], 0, 0, 0);
                    }
                }
            }
            cur ^= 1;
        } // it

        if (ck == 0) sL[ch][cq] = l_run;
        __syncthreads(); // B5: final PV done; sL ready

        // ---- head mixing: 4 barriered stages over (i_pv, kh) into sO ----
        float* sO = sS;
#pragma unroll
        for (int st = 0; st < 4; ++st) {
            if (i_pv == (st >> 1) && kh == (st & 1)) {
#pragma unroll
                for (int mt = 0; mt < 2; ++mt)
#pragma unroll
                    for (int r = 0; r < 4; ++r) {
                        int row = mt * 16 + crow4 + r;
                        float cc = mixc / sL[i_pv][row];
#pragma unroll
                        for (int nt = 0; nt < 4; ++nt) {
                            int col = nt * 16 + lrow;
                            float val = acc[mt][nt][r] * cc;
                            if (st == 0) sO[(j_pv * 32 + row) * 68 + col] = val;
                            else         sO[(j_pv * 32 + row) * 68 + col] += val;
                        }
                    }
            }
            __syncthreads();
        }

        // ---- LayerNorm over D + store (2 items/thread) ----
        {
            const float4* G4 = (const float4*)GAM;
            const float4* B4 = (const float4*)BET;
#pragma unroll
            for (int itl = 0; itl < 2; ++itl) {
                int pidx = tid + (itl << 9);
                int d4 = pidx & 15, rowj = pidx >> 4; // 0..63
                int j = rowj >> 5, qq = rowj & 31;
                float4 o = *(const float4*)&sO[rowj * 68 + (d4 << 2)];
                float s1 = o.x + o.y + o.z + o.w;
                float s2 = o.x * o.x + o.y * o.y + o.z * o.z + o.w * o.w;
#pragma unroll
                for (int off = 1; off < 16; off <<= 1) {
                    s1 += __shfl_xor(s1, off);
                    s2 += __shfl_xor(s2, off);
                }
                float mean = s1 * (1.f / 64.f);
                float var = s2 * (1.f / 64.f) - mean * mean;
                float rs = rsqrtf(var + 1e-5f);
                float4 gm = G4[d4], bt = B4[d4];
                float4 ov;
                ov.x = (o.x - mean) * rs * gm.x + bt.x;
                ov.y = (o.y - mean) * rs * gm.y + bt.y;
                ov.z = (o.z - mean) * rs * gm.z + bt.z;
                ov.w = (o.w - mean) * rs * gm.w + bt.w;
                *(float4*)&OUT[(((2 * g + j) * SS + q0 + qq) << 6) + (d4 << 2)] = ov;
            }
        }
    } // ti
}

extern "C" void kernel_launch(void* const* d_in, const int* in_sizes, int n_in,
                              void* d_out, int out_size, void* d_ws, size_t ws_size,
                              hipStream_t stream) {
    const float* q = (const float*)d_in[0];
    const float* k = (const float*)d_in[1];
    const float* v = (const float*)d_in[2];
    const float* cw = (const float*)d_in[3];
    const float* cb = (const float*)d_in[4];
    const float* mix = (const float*)d_in[5];
    const float* gam = (const float*)d_in[6];
    const float* bet = (const float*)d_in[7];
    float* out = (float*)d_out;

    dim3 grid(8 * 32);   // 256 blocks; ~139 KB LDS guarantees 1 block/CU
    dim3 block(512);     // 8 waves = 2 waves/SIMD
    hipLaunchKernelGGL(mta_v7, grid, block, 0, stream,
                       q, k, v, cw, cb, mix, gam, bet, out);
}

// Round 8
// 234.336 us; speedup vs baseline: 1.8370x; 1.8370x over previous
//
#include <hip/hip_runtime.h>
#include <math.h>

#define SS 2048
#define QP 72   // bf16 pitch sQ (48 rows/head)
#define KP 72   // bf16 pitch sK (80 rows/head)
#define VP 72   // bf16 pitch sVt (64 d-rows/head)
#define SP 84   // f32 pitch sS (48 rows/head, 80 cols)
#define PP 72   // bf16 pitch sP (32 rows/head, 64 cols)

typedef __attribute__((ext_vector_type(8))) short s8v;
typedef __attribute__((ext_vector_type(4))) float f4v;

__device__ __forceinline__ unsigned short f2b(float x) {
    union { float f; unsigned u; } v; v.f = x;
    unsigned r = v.u + 0x7FFFu + ((v.u >> 16) & 1u);
    return (unsigned short)(r >> 16);
}

__device__ __forceinline__ unsigned long long pack4(float4 v) {
    return (unsigned long long)f2b(v.x) | ((unsigned long long)f2b(v.y) << 16)
         | ((unsigned long long)f2b(v.z) << 32) | ((unsigned long long)f2b(v.w) << 48);
}

__global__ __launch_bounds__(512, 2)
void mta_v8(const float* __restrict__ Q, const float* __restrict__ K,
            const float* __restrict__ V, const float* __restrict__ CW,
            const float* __restrict__ CB, const float* __restrict__ MIX,
            const float* __restrict__ GAM, const float* __restrict__ BET,
            float* __restrict__ OUT)
{
    __shared__ __align__(16) unsigned short sQ[96 * QP];       // 13824 B
    __shared__ __align__(16) unsigned short sK[2][160 * KP];   // 2 x 23040 B
    __shared__ __align__(16) unsigned short sVt[2][128 * VP];  // 2 x 18432 B
    __shared__ __align__(16) float sS[96 * SP];                // 32256 B (reused as sO, pitch 68)
    __shared__ __align__(16) unsigned short sP[64 * PP];       // 9216 B
    __shared__ float sResc[2][32];
    __shared__ float sL[2][32];
    __shared__ float sW[2][66];
    __shared__ float sB[2];
    // ~139 KB -> hardware-guaranteed 1 block/CU

    const int tid = threadIdx.x;
    const int g = blockIdx.x & 7;
    const int u = blockIdx.x >> 3;   // 0..31

    const int wv = tid >> 6, lane = tid & 63;
    const int lrow = lane & 15;            // MFMA A/B row, C col
    const int lk8 = (lane >> 4) << 3;      // MFMA k-offset
    const int crow4 = (lane >> 4) << 2;    // MFMA C row base

    // conv/softmax mapping: 2 heads x 32 rows x 8 key-octs
    const int ch = tid >> 8;
    const int cq = (tid >> 3) & 31;
    const int ck = tid & 7;

    // PV wave role: (i = source head, j = dest head, kh = key half)
    const int i_pv = wv >> 2, j_pv = (wv >> 1) & 1, kh = wv & 1;

    for (int idx = tid; idx < 132; idx += 512) {
        int h = idx / 66, w = idx - h * 66;
        sW[h][w] = CW[(2 * g + h) * 66 + w];
    }
    if (tid < 2) sB[tid] = CB[2 * g + tid];
    const float mixc = MIX[g * 4 + i_pv * 2 + j_pv];

    const float4* Q4 = (const float4*)Q;
    const float4* K4 = (const float4*)K;
    const float4* V4 = (const float4*)V;

    for (int ti = 0; ti < 2; ++ti) {
        const int tile = ti ? u : (63 - u);   // per-block iteration total constant (33)
        const int q0 = tile << 5;
        __syncthreads(); // P0: prev-ti consumers done before restaging sQ / buffers

        // ---- stage extended Q tile (rows q0-2 .. q0+45), bf16 ----
        for (int idx = tid; idx < 1536; idx += 512) {
            int h = idx / 768, rem = idx - h * 768;
            int e = rem >> 4, d4 = rem & 15;
            int r = q0 - 2 + e;
            float4 val = make_float4(0.f, 0.f, 0.f, 0.f);
            if (r >= 0 && r < SS) val = Q4[((2 * g + h) * SS + r) * 16 + d4];
            *(unsigned long long*)&sQ[(h * 48 + e) * QP + (d4 << 2)] = pack4(val);
        }
        // ---- direct-stage K/V buffer 0 (k0 = 0) ----
        for (int idx = tid; idx < 2560; idx += 512) {
            int h = idx / 1280, rem = idx - h * 1280;
            int e = rem >> 4, d4 = rem & 15;
            int c = -5 + e;
            float4 val = make_float4(0.f, 0.f, 0.f, 0.f);
            if (e < 74 && c >= 0 && c < SS) val = K4[((2 * g + h) * SS + c) * 16 + d4];
            *(unsigned long long*)&sK[0][(h * 80 + e) * KP + (d4 << 2)] = pack4(val);
        }
        for (int idx = tid; idx < 2048; idx += 512) {
            int h = idx >> 10, d4 = (idx >> 6) & 15, kk = idx & 63;
            float4 val = V4[((2 * g + h) * SS + kk) * 16 + d4];
            int d = d4 << 2;
            sVt[0][(h * 64 + d + 0) * VP + kk] = f2b(val.x);
            sVt[0][(h * 64 + d + 1) * VP + kk] = f2b(val.y);
            sVt[0][(h * 64 + d + 2) * VP + kk] = f2b(val.z);
            sVt[0][(h * 64 + d + 3) * VP + kk] = f2b(val.w);
        }

        f4v acc[2][4];
#pragma unroll
        for (int mt = 0; mt < 2; ++mt)
#pragma unroll
            for (int nt = 0; nt < 4; ++nt) acc[mt][nt] = f4v{0.f, 0.f, 0.f, 0.f};
        float m_run = -INFINITY, l_run = 0.f;
        int cur = 0;

        __syncthreads(); // P1: buffer 0 + Q staged

        const int iters = (tile >> 1) + 1;   // 64 keys per iteration
        for (int it = 0; it < iters; ++it) {
            const int k0 = it << 6;
            const bool pf = (it + 1) < iters;
            const int k0n = (it + 1) << 6;
            const int nxt = cur ^ 1;

            // ---- (B) scores: 2 heads x 3 m-tiles x 5 n-tiles, K=64 ----
            for (int job = wv; job < 30; job += 8) {
                int h = job / 15, r15 = job - h * 15;
                int mt = r15 / 5, nt = r15 - mt * 5;
                const unsigned short* ap = &sQ[(h * 48 + mt * 16 + lrow) * QP + lk8];
                const unsigned short* bp = &sK[cur][(h * 80 + nt * 16 + lrow) * KP + lk8];
                f4v c = f4v{0.f, 0.f, 0.f, 0.f};
                c = __builtin_amdgcn_mfma_f32_16x16x32_bf16(*(const s8v*)ap,
                                                            *(const s8v*)bp, c, 0, 0, 0);
                c = __builtin_amdgcn_mfma_f32_16x16x32_bf16(*(const s8v*)(ap + 32),
                                                            *(const s8v*)(bp + 32), c, 0, 0, 0);
                int col = nt * 16 + lrow;
                int cab = k0 - 5 + col;
                int rbase = mt * 16 + crow4;
#pragma unroll
                for (int r = 0; r < 4; ++r)
                    sS[(h * 48 + rbase + r) * SP + col] = (cab <= q0 - 2 + rbase + r) ? c[r] * 0.125f : 0.f;
            }
            __syncthreads(); // X: sS published; prev PV done with sP/sResc

            // ---- (C) conv+softmax, with next-tile K/V staged through phase-local regs ----
            {
                // issue prefetch loads FIRST (latency hides under conv below)
                float4 kreg[5], vreg[4];
#pragma unroll
                for (int n = 0; n < 5; ++n) {
                    int idx = tid + (n << 9);
                    int h = idx / 1280, rem = idx - h * 1280;
                    int e = rem >> 4, d4 = rem & 15;
                    int c = k0n - 5 + e;
                    kreg[n] = make_float4(0.f, 0.f, 0.f, 0.f);
                    if (pf && e < 74 && c >= 0 && c < SS)
                        kreg[n] = K4[((2 * g + h) * SS + c) * 16 + d4];
                }
#pragma unroll
                for (int n = 0; n < 4; ++n) {
                    int idx = tid + (n << 9);
                    int h = idx >> 10, d4 = (idx >> 6) & 15, kk = idx & 63;
                    vreg[n] = make_float4(0.f, 0.f, 0.f, 0.f);
                    if (pf)
                        vreg[n] = V4[((2 * g + h) * SS + k0n + kk) * 16 + d4];
                }

                // conv (8 keys/thread) + causal re-mask + online softmax
                const int c0 = ck << 3;
                float a8[8];
                float bias = sB[ch];
#pragma unroll
                for (int kk = 0; kk < 8; ++kk) a8[kk] = bias;
#pragma unroll
                for (int i = 0; i < 6; ++i) {
                    const float* base = &sS[(ch * 48 + cq + i) * SP + c0];
                    float4 x0 = *(const float4*)&base[0];
                    float4 x1 = *(const float4*)&base[4];
                    float4 x2 = *(const float4*)&base[8];
                    float4 x3 = *(const float4*)&base[12];
                    float4 x4 = *(const float4*)&base[16];
                    float s[20] = {x0.x, x0.y, x0.z, x0.w, x1.x, x1.y, x1.z, x1.w,
                                   x2.x, x2.y, x2.z, x2.w, x3.x, x3.y, x3.z, x3.w,
                                   x4.x, x4.y, x4.z, x4.w};
                    float wr[11];
#pragma unroll
                    for (int jj = 0; jj < 11; ++jj) wr[jj] = sW[ch][i * 11 + jj];
#pragma unroll
                    for (int kk = 0; kk < 8; ++kk)
#pragma unroll
                        for (int jj = 0; jj < 11; ++jj)
                            a8[kk] = fmaf(wr[jj], s[kk + jj], a8[kk]);
                }
                const int r_abs = q0 + cq;
                float tmax = -INFINITY;
#pragma unroll
                for (int kk = 0; kk < 8; ++kk) {
                    int cab = k0 + c0 + kk;
                    if (cab > r_abs) a8[kk] = -1e9f;
                    tmax = fmaxf(tmax, a8[kk]);
                }
                tmax = fmaxf(tmax, __shfl_xor(tmax, 1));
                tmax = fmaxf(tmax, __shfl_xor(tmax, 2));
                tmax = fmaxf(tmax, __shfl_xor(tmax, 4));
                float mnew = fmaxf(m_run, tmax);
                float resc = __expf(m_run - mnew); // first iter: exp(-inf)=0
                float p[8];
                float psum = 0.f;
#pragma unroll
                for (int kk = 0; kk < 8; ++kk) {
                    p[kk] = __expf(a8[kk] - mnew);
                    psum += p[kk];
                }
                psum += __shfl_xor(psum, 1);
                psum += __shfl_xor(psum, 2);
                psum += __shfl_xor(psum, 4);
                l_run = l_run * resc + psum;
                m_run = mnew;
                if (ck == 0) sResc[ch][cq] = resc;
                s8v pv;
#pragma unroll
                for (int kk = 0; kk < 8; ++kk) pv[kk] = (short)f2b(p[kk]);
                *(s8v*)&sP[(ch * 32 + cq) * PP + c0] = pv;

                // drain prefetch into the alternate buffers (regs die here)
                if (pf) {
#pragma unroll
                    for (int n = 0; n < 5; ++n) {
                        int idx = tid + (n << 9);
                        int h = idx / 1280, rem = idx - h * 1280;
                        int e = rem >> 4, d4 = rem & 15;
                        *(unsigned long long*)&sK[nxt][(h * 80 + e) * KP + (d4 << 2)] = pack4(kreg[n]);
                    }
#pragma unroll
                    for (int n = 0; n < 4; ++n) {
                        int idx = tid + (n << 9);
                        int h = idx >> 10, d4 = (idx >> 6) & 15, kk = idx & 63;
                        int d = d4 << 2;
                        sVt[nxt][(h * 64 + d + 0) * VP + kk] = f2b(vreg[n].x);
                        sVt[nxt][(h * 64 + d + 1) * VP + kk] = f2b(vreg[n].y);
                        sVt[nxt][(h * 64 + d + 2) * VP + kk] = f2b(vreg[n].z);
                        sVt[nxt][(h * 64 + d + 3) * VP + kk] = f2b(vreg[n].w);
                    }
                }
            }
            __syncthreads(); // Y: sP/sResc + next buffers published

            // ---- (E) PV: wave (i,j,kh): acc += P_i[kh half] @ V_j ----
            {
#pragma unroll
                for (int mt = 0; mt < 2; ++mt)
#pragma unroll
                    for (int r = 0; r < 4; ++r) {
                        float f = sResc[i_pv][mt * 16 + crow4 + r];
#pragma unroll
                        for (int nt = 0; nt < 4; ++nt) acc[mt][nt][r] *= f;
                    }
#pragma unroll
                for (int mt = 0; mt < 2; ++mt) {
                    s8v a = *(const s8v*)&sP[(i_pv * 32 + mt * 16 + lrow) * PP + (kh << 5) + lk8];
#pragma unroll
                    for (int nt = 0; nt < 4; ++nt) {
                        s8v b = *(const s8v*)&sVt[cur][(j_pv * 64 + nt * 16 + lrow) * VP + (kh << 5) + lk8];
                        acc[mt][nt] = __builtin_amdgcn_mfma_f32_16x16x32_bf16(a, b, acc[mt][nt], 0, 0, 0);
                    }
                }
            }
            cur = nxt;
            // no barrier: next (B) writes sS (untouched by E) and reads sK[new cur]
            // (published at Y); sP/sResc next written only after next X.
        } // it

        if (ck == 0) sL[ch][cq] = l_run;
        __syncthreads(); // B5: final PV done; sL ready; conv-phase sS reads done

        // ---- head mixing: 4 barriered stages over (i_pv, kh) into sO ----
        float* sO = sS;
#pragma unroll
        for (int st = 0; st < 4; ++st) {
            if (i_pv == (st >> 1) && kh == (st & 1)) {
#pragma unroll
                for (int mt = 0; mt < 2; ++mt)
#pragma unroll
                    for (int r = 0; r < 4; ++r) {
                        int row = mt * 16 + crow4 + r;
                        float cc = mixc / sL[i_pv][row];
#pragma unroll
                        for (int nt = 0; nt < 4; ++nt) {
                            int col = nt * 16 + lrow;
                            float val = acc[mt][nt][r] * cc;
                            if (st == 0) sO[(j_pv * 32 + row) * 68 + col] = val;
                            else         sO[(j_pv * 32 + row) * 68 + col] += val;
                        }
                    }
            }
            __syncthreads();
        }

        // ---- LayerNorm over D + store (2 items/thread) ----
        {
            const float4* G4 = (const float4*)GAM;
            const float4* B4 = (const float4*)BET;
#pragma unroll
            for (int itl = 0; itl < 2; ++itl) {
                int pidx = tid + (itl << 9);
                int d4 = pidx & 15, rowj = pidx >> 4; // 0..63
                int j = rowj >> 5, qq = rowj & 31;
                float4 o = *(const float4*)&sO[rowj * 68 + (d4 << 2)];
                float s1 = o.x + o.y + o.z + o.w;
                float s2 = o.x * o.x + o.y * o.y + o.z * o.z + o.w * o.w;
#pragma unroll
                for (int off = 1; off < 16; off <<= 1) {
                    s1 += __shfl_xor(s1, off);
                    s2 += __shfl_xor(s2, off);
                }
                float mean = s1 * (1.f / 64.f);
                float var = s2 * (1.f / 64.f) - mean * mean;
                float rs = rsqrtf(var + 1e-5f);
                float4 gm = G4[d4], bt = B4[d4];
                float4 ov;
                ov.x = (o.x - mean) * rs * gm.x + bt.x;
                ov.y = (o.y - mean) * rs * gm.y + bt.y;
                ov.z = (o.z - mean) * rs * gm.z + bt.z;
                ov.w = (o.w - mean) * rs * gm.w + bt.w;
                *(float4*)&OUT[(((2 * g + j) * SS + q0 + qq) << 6) + (d4 << 2)] = ov;
            }
        }
    } // ti
}

extern "C" void kernel_launch(void* const* d_in, const int* in_sizes, int n_in,
                              void* d_out, int out_size, void* d_ws, size_t ws_size,
                              hipStream_t stream) {
    const float* q = (const float*)d_in[0];
    const float* k = (const float*)d_in[1];
    const float* v = (const float*)d_in[2];
    const float* cw = (const float*)d_in[3];
    const float* cb = (const float*)d_in[4];
    const float* mix = (const float*)d_in[5];
    const float* gam = (const float*)d_in[6];
    const float* bet = (const float*)d_in[7];
    float* out = (float*)d_out;

    dim3 grid(8 * 32);   // 256 blocks; ~139 KB LDS guarantees 1 block/CU
    dim3 block(512);     // 8 waves = 2 waves/SIMD
    hipLaunchKernelGGL(mta_v8, grid, block, 0, stream,
                       q, k, v, cw, cb, mix, gam, bet, out);
}

// Round 9
// 125.293 us; speedup vs baseline: 3.4357x; 1.8703x over previous
//
#include <hip/hip_runtime.h>
#include <math.h>

#define SS 2048
#define QP 72   // bf16 pitch sQ (48 rows/head)
#define KP 72   // bf16 pitch sK (80 rows/head)
#define VP 72   // bf16 pitch sVt (64 d-rows/head)
#define SFP 88  // f16 pitch sSf (48 rows/head, 80 cols used)
#define PP 72   // bf16 pitch sP (32 rows/head, 64 cols)

typedef __attribute__((ext_vector_type(8))) short s8v;
typedef __attribute__((ext_vector_type(8))) _Float16 h8v;
typedef __attribute__((ext_vector_type(4))) float f4v;

__device__ __forceinline__ unsigned short f2b(float x) {
    union { float f; unsigned u; } v; v.f = x;
    unsigned r = v.u + 0x7FFFu + ((v.u >> 16) & 1u);
    return (unsigned short)(r >> 16);
}

__device__ __forceinline__ unsigned long long pack4(float4 v) {
    return (unsigned long long)f2b(v.x) | ((unsigned long long)f2b(v.y) << 16)
         | ((unsigned long long)f2b(v.z) << 32) | ((unsigned long long)f2b(v.w) << 48);
}

__global__ __launch_bounds__(512, 2)
void mta_v9(const float* __restrict__ Q, const float* __restrict__ K,
            const float* __restrict__ V, const float* __restrict__ CW,
            const float* __restrict__ CB, const float* __restrict__ MIX,
            const float* __restrict__ GAM, const float* __restrict__ BET,
            float* __restrict__ OUT)
{
    __shared__ __align__(16) unsigned short sQ[96 * QP];       // 13824 B
    __shared__ __align__(16) unsigned short sK[2][160 * KP];   // 2 x 23040 B
    __shared__ __align__(16) unsigned short sVt[2][128 * VP];  // 2 x 18432 B
    __shared__ __align__(16) _Float16 sSf[96 * SFP];           // 16896 B (masked f16 scores)
    __shared__ __align__(16) unsigned short sP[64 * PP];       // 9216 B
    __shared__ float sResc[2][32];
    __shared__ float sL[2][32];
    __shared__ float sW2[2][66];
    __shared__ float sB2[2];
    // ~121 KB -> hardware-guaranteed 1 block/CU

    const int tid = threadIdx.x;
    const int g = blockIdx.x & 7;
    const int u = blockIdx.x >> 3;   // 0..31

    const int wv = tid >> 6, lane = tid & 63;
    const int lrow = lane & 15;            // MFMA A/B row (M/N idx), C col
    const int lk8 = (lane >> 4) << 3;      // MFMA contraction offset
    const int crow4 = (lane >> 4) << 2;    // MFMA C row base

    // PV wave role: (i = source head, j = dest head, kh = key half)
    const int i_pv = wv >> 2, j_pv = (wv >> 1) & 1, kh = wv & 1;
    // conv wave role (waves 0-3): (head, m-tile)
    const int hC = wv >> 1, mtw = wv & 1;

    for (int idx = tid; idx < 132; idx += 512) {
        int h = idx / 66, w = idx - h * 66;
        sW2[h][w] = CW[(2 * g + h) * 66 + w];
    }
    if (tid < 2) sB2[tid] = CB[2 * g + tid];
    const float mixc = MIX[g * 4 + i_pv * 2 + j_pv];
    __syncthreads();

    // ---- build T fragments in registers (waves 0-3): T_i[n=lrow][z] = w[i][z-n] ----
    h8v tf[6];
    float biasC = 0.f;
    if (wv < 4) {
        biasC = sB2[hC];
#pragma unroll
        for (int i = 0; i < 6; ++i)
#pragma unroll
            for (int e = 0; e < 8; ++e) {
                int d = lk8 + e - lrow;
                tf[i][e] = (d >= 0 && d <= 10) ? (_Float16)sW2[hC][i * 11 + d] : (_Float16)0.f;
            }
    }

    const float4* Q4 = (const float4*)Q;
    const float4* K4 = (const float4*)K;
    const float4* V4 = (const float4*)V;

    for (int ti = 0; ti < 2; ++ti) {
        const int tile = ti ? u : (63 - u);   // per-block iteration total constant (33)
        const int q0 = tile << 5;
        __syncthreads(); // P0: prev-ti consumers done before restaging

        // ---- stage extended Q tile (rows q0-2 .. q0+45), bf16 ----
        for (int idx = tid; idx < 1536; idx += 512) {
            int h = idx / 768, rem = idx - h * 768;
            int e = rem >> 4, d4 = rem & 15;
            int r = q0 - 2 + e;
            float4 val = make_float4(0.f, 0.f, 0.f, 0.f);
            if (r >= 0 && r < SS) val = Q4[((2 * g + h) * SS + r) * 16 + d4];
            *(unsigned long long*)&sQ[(h * 48 + e) * QP + (d4 << 2)] = pack4(val);
        }
        // ---- direct-stage K/V buffer 0 (k0 = 0) ----
        for (int idx = tid; idx < 2560; idx += 512) {
            int h = idx / 1280, rem = idx - h * 1280;
            int e = rem >> 4, d4 = rem & 15;
            int c = -5 + e;
            float4 val = make_float4(0.f, 0.f, 0.f, 0.f);
            if (e < 74 && c >= 0 && c < SS) val = K4[((2 * g + h) * SS + c) * 16 + d4];
            *(unsigned long long*)&sK[0][(h * 80 + e) * KP + (d4 << 2)] = pack4(val);
        }
        for (int idx = tid; idx < 2048; idx += 512) {
            int h = idx >> 10, d4 = (idx >> 6) & 15, kk = idx & 63;
            float4 val = V4[((2 * g + h) * SS + kk) * 16 + d4];
            int d = d4 << 2;
            sVt[0][(h * 64 + d + 0) * VP + kk] = f2b(val.x);
            sVt[0][(h * 64 + d + 1) * VP + kk] = f2b(val.y);
            sVt[0][(h * 64 + d + 2) * VP + kk] = f2b(val.z);
            sVt[0][(h * 64 + d + 3) * VP + kk] = f2b(val.w);
        }

        f4v acc[2][4];
#pragma unroll
        for (int mt = 0; mt < 2; ++mt)
#pragma unroll
            for (int nt = 0; nt < 4; ++nt) acc[mt][nt] = f4v{0.f, 0.f, 0.f, 0.f};
        float m_run[4], l_run[4];
#pragma unroll
        for (int r = 0; r < 4; ++r) { m_run[r] = -INFINITY; l_run[r] = 0.f; }
        int cur = 0;

        __syncthreads(); // P1: buffer 0 + Q staged

        const int iters = (tile >> 1) + 1;   // 64 keys per iteration
        for (int it = 0; it < iters; ++it) {
            const int k0 = it << 6;
            const bool pf = (it + 1) < iters;
            const int k0n = (it + 1) << 6;
            const int nxt = cur ^ 1;

            // ---- (B) scores: 2 heads x 3 m-tiles x 5 n-tiles, K=64, masked f16 out ----
            for (int job = wv; job < 30; job += 8) {
                int h = job / 15, r15 = job - h * 15;
                int mt = r15 / 5, nt = r15 - mt * 5;
                const unsigned short* ap = &sQ[(h * 48 + mt * 16 + lrow) * QP + lk8];
                const unsigned short* bp = &sK[cur][(h * 80 + nt * 16 + lrow) * KP + lk8];
                f4v c = f4v{0.f, 0.f, 0.f, 0.f};
                c = __builtin_amdgcn_mfma_f32_16x16x32_bf16(*(const s8v*)ap,
                                                            *(const s8v*)bp, c, 0, 0, 0);
                c = __builtin_amdgcn_mfma_f32_16x16x32_bf16(*(const s8v*)(ap + 32),
                                                            *(const s8v*)(bp + 32), c, 0, 0, 0);
                int col = nt * 16 + lrow;
                int cab = k0 - 5 + col;
                int rbase = mt * 16 + crow4;
#pragma unroll
                for (int r = 0; r < 4; ++r)
                    sSf[(h * 48 + rbase + r) * SFP + col] =
                        (_Float16)((cab <= q0 - 2 + rbase + r) ? c[r] * 0.125f : 0.f);
            }
            __syncthreads(); // X: sSf published; prev PV done with sP/sResc

            // ---- (C) split: waves 0-3 conv(MFMA)+softmax; waves 4-7 K/V prefetch ----
            if (wv < 4) {
                f4v cc[4];
#pragma unroll
                for (int ct = 0; ct < 4; ++ct) {
                    f4v c = f4v{0.f, 0.f, 0.f, 0.f};
#pragma unroll
                    for (int i = 0; i < 6; ++i) {
                        h8v a = *(const h8v*)&sSf[(hC * 48 + mtw * 16 + i + lrow) * SFP + ct * 16 + lk8];
                        c = __builtin_amdgcn_mfma_f32_16x16x32_f16(a, tf[i], c, 0, 0, 0);
                    }
                    cc[ct] = c;
                }
                const int rowa0 = q0 + mtw * 16 + crow4;
#pragma unroll
                for (int r = 0; r < 4; ++r) {
                    float tm = -INFINITY;
#pragma unroll
                    for (int ct = 0; ct < 4; ++ct) {
                        float v = cc[ct][r] + biasC;
                        int ca = k0 + ct * 16 + lrow;
                        if (ca > rowa0 + r) v = -1e9f;
                        cc[ct][r] = v;
                        tm = fmaxf(tm, v);
                    }
                    tm = fmaxf(tm, __shfl_xor(tm, 1));
                    tm = fmaxf(tm, __shfl_xor(tm, 2));
                    tm = fmaxf(tm, __shfl_xor(tm, 4));
                    tm = fmaxf(tm, __shfl_xor(tm, 8));
                    float mnew = fmaxf(m_run[r], tm);
                    float resc = __expf(m_run[r] - mnew); // first iter: exp(-inf)=0
                    m_run[r] = mnew;
                    float ps = 0.f;
#pragma unroll
                    for (int ct = 0; ct < 4; ++ct) {
                        float p = __expf(cc[ct][r] - mnew);
                        cc[ct][r] = p;
                        ps += p;
                    }
                    ps += __shfl_xor(ps, 1);
                    ps += __shfl_xor(ps, 2);
                    ps += __shfl_xor(ps, 4);
                    ps += __shfl_xor(ps, 8);
                    l_run[r] = l_run[r] * resc + ps;
                    if (lrow == 0) sResc[hC][mtw * 16 + crow4 + r] = resc;
                }
#pragma unroll
                for (int ct = 0; ct < 4; ++ct)
#pragma unroll
                    for (int r = 0; r < 4; ++r)
                        sP[(hC * 32 + mtw * 16 + crow4 + r) * PP + ct * 16 + lrow] = f2b(cc[ct][r]);
            } else if (pf) {
                const int stid = ((wv - 4) << 6) + lane; // 0..255
                float4 kreg[10], vreg[8];
#pragma unroll
                for (int n = 0; n < 10; ++n) {
                    int idx = stid + (n << 8);
                    int h = idx / 1280, rem = idx - h * 1280;
                    int e = rem >> 4, d4 = rem & 15;
                    int c = k0n - 5 + e;
                    kreg[n] = make_float4(0.f, 0.f, 0.f, 0.f);
                    if (e < 74 && c >= 0 && c < SS)
                        kreg[n] = K4[((2 * g + h) * SS + c) * 16 + d4];
                }
#pragma unroll
                for (int n = 0; n < 8; ++n) {
                    int idx = stid + (n << 8);
                    int h = idx >> 10, d4 = (idx >> 6) & 15, kk = idx & 63;
                    vreg[n] = V4[((2 * g + h) * SS + k0n + kk) * 16 + d4];
                }
#pragma unroll
                for (int n = 0; n < 10; ++n) {
                    int idx = stid + (n << 8);
                    int h = idx / 1280, rem = idx - h * 1280;
                    int e = rem >> 4, d4 = rem & 15;
                    *(unsigned long long*)&sK[nxt][(h * 80 + e) * KP + (d4 << 2)] = pack4(kreg[n]);
                }
#pragma unroll
                for (int n = 0; n < 8; ++n) {
                    int idx = stid + (n << 8);
                    int h = idx >> 10, d4 = (idx >> 6) & 15, kk = idx & 63;
                    int d = d4 << 2;
                    sVt[nxt][(h * 64 + d + 0) * VP + kk] = f2b(vreg[n].x);
                    sVt[nxt][(h * 64 + d + 1) * VP + kk] = f2b(vreg[n].y);
                    sVt[nxt][(h * 64 + d + 2) * VP + kk] = f2b(vreg[n].z);
                    sVt[nxt][(h * 64 + d + 3) * VP + kk] = f2b(vreg[n].w);
                }
            }
            __syncthreads(); // Y: sP/sResc + next buffers published

            // ---- (E) PV: wave (i,j,kh): acc += P_i[kh half] @ V_j ----
            {
#pragma unroll
                for (int mt = 0; mt < 2; ++mt)
#pragma unroll
                    for (int r = 0; r < 4; ++r) {
                        float f = sResc[i_pv][mt * 16 + crow4 + r];
#pragma unroll
                        for (int nt = 0; nt < 4; ++nt) acc[mt][nt][r] *= f;
                    }
#pragma unroll
                for (int mt = 0; mt < 2; ++mt) {
                    s8v a = *(const s8v*)&sP[(i_pv * 32 + mt * 16 + lrow) * PP + (kh << 5) + lk8];
#pragma unroll
                    for (int nt = 0; nt < 4; ++nt) {
                        s8v b = *(const s8v*)&sVt[cur][(j_pv * 64 + nt * 16 + lrow) * VP + (kh << 5) + lk8];
                        acc[mt][nt] = __builtin_amdgcn_mfma_f32_16x16x32_bf16(a, b, acc[mt][nt], 0, 0, 0);
                    }
                }
            }
            cur = nxt;
            // no barrier: next (B) writes sSf (not touched by E) and reads sK[new cur]
            // (published at Y); sP/sResc/sVt next rewritten only after next X.
        } // it

        if (wv < 4 && lrow == 0) {
#pragma unroll
            for (int r = 0; r < 4; ++r) sL[hC][mtw * 16 + crow4 + r] = l_run[r];
        }
        __syncthreads(); // B5: final PV done; sL ready

        // ---- head mixing: 4 barriered stages over (i_pv, kh) into sO (reuse sK) ----
        float* sO = (float*)&sK[0][0];
#pragma unroll
        for (int st = 0; st < 4; ++st) {
            if (i_pv == (st >> 1) && kh == (st & 1)) {
#pragma unroll
                for (int mt = 0; mt < 2; ++mt)
#pragma unroll
                    for (int r = 0; r < 4; ++r) {
                        int row = mt * 16 + crow4 + r;
                        float cc = mixc / sL[i_pv][row];
#pragma unroll
                        for (int nt = 0; nt < 4; ++nt) {
                            int col = nt * 16 + lrow;
                            float val = acc[mt][nt][r] * cc;
                            if (st == 0) sO[(j_pv * 32 + row) * 68 + col] = val;
                            else         sO[(j_pv * 32 + row) * 68 + col] += val;
                        }
                    }
            }
            __syncthreads();
        }

        // ---- LayerNorm over D + store (2 items/thread) ----
        {
            const float4* G4 = (const float4*)GAM;
            const float4* B4 = (const float4*)BET;
#pragma unroll
            for (int itl = 0; itl < 2; ++itl) {
                int pidx = tid + (itl << 9);
                int d4 = pidx & 15, rowj = pidx >> 4; // 0..63
                int j = rowj >> 5, qq = rowj & 31;
                float4 o = *(const float4*)&sO[rowj * 68 + (d4 << 2)];
                float s1 = o.x + o.y + o.z + o.w;
                float s2 = o.x * o.x + o.y * o.y + o.z * o.z + o.w * o.w;
#pragma unroll
                for (int off = 1; off < 16; off <<= 1) {
                    s1 += __shfl_xor(s1, off);
                    s2 += __shfl_xor(s2, off);
                }
                float mean = s1 * (1.f / 64.f);
                float var = s2 * (1.f / 64.f) - mean * mean;
                float rs = rsqrtf(var + 1e-5f);
                float4 gm = G4[d4], bt = B4[d4];
                float4 ov;
                ov.x = (o.x - mean) * rs * gm.x + bt.x;
                ov.y = (o.y - mean) * rs * gm.y + bt.y;
                ov.z = (o.z - mean) * rs * gm.z + bt.z;
                ov.w = (o.w - mean) * rs * gm.w + bt.w;
                *(float4*)&OUT[(((2 * g + j) * SS + q0 + qq) << 6) + (d4 << 2)] = ov;
            }
        }
    } // ti
}

extern "C" void kernel_launch(void* const* d_in, const int* in_sizes, int n_in,
                              void* d_out, int out_size, void* d_ws, size_t ws_size,
                              hipStream_t stream) {
    const float* q = (const float*)d_in[0];
    const float* k = (const float*)d_in[1];
    const float* v = (const float*)d_in[2];
    const float* cw = (const float*)d_in[3];
    const float* cb = (const float*)d_in[4];
    const float* mix = (const float*)d_in[5];
    const float* gam = (const float*)d_in[6];
    const float* bet = (const float*)d_in[7];
    float* out = (float*)d_out;

    dim3 grid(8 * 32);   // 256 blocks; ~121 KB LDS guarantees 1 block/CU
    dim3 block(512);     // 8 waves = 2 waves/SIMD
    hipLaunchKernelGGL(mta_v9, grid, block, 0, stream,
                       q, k, v, cw, cb, mix, gam, bet, out);
}